// Round 15
// baseline (197.815 us; speedup 1.0000x reference)
//
#include <hip/hip_runtime.h>
#include <math.h>

// Shapes: B=8, T=16, H=64, W=64, D=256, DK=128, TOP_K=4
// pixels N = B*H*W = 32768 (4096 per batch)
//
// Factorization: out = (sum_t attn_t * hist_t) @ (Wv@Wo)
//                score_t = (q @ (Wq@Wk^T)) . hist_t / sqrt(128)
// Score path fp32 (top-k precision-critical); out-projection bf16 MFMA.
//
// R15: phase 1 split into (1a) LINEAR score pass -- wave w streams t in
// {w,w+4,w+8,w+12} over the block's 64 pixels as contiguous 64KB runs
// (copy-benchmark access shape, vs R13's 16 strided streams / wave),
// (1b) top-4+softmax from LDS scores (R13's rank trick), (1c) gather of
// the 4 winner rows per pixel (128MB, partly L3-hit) -> hbar. 2 barriers.

typedef __attribute__((ext_vector_type(8))) short bf16x8;
typedef __attribute__((ext_vector_type(4))) float f32x4;

__device__ inline unsigned short f2bf(float f) {
  union { float f; unsigned u; } v; v.f = f;
  unsigned r = (v.u + 0x7FFF + ((v.u >> 16) & 1)) >> 16;  // RNE
  return (unsigned short)r;
}

// ---------------- Kernel P: M1 = Wq@Wk^T, M2F = bf16-frag(Wv@Wo) ----------
__global__ __launch_bounds__(256) void precompute_weights(
    const float* __restrict__ Wq, const float* __restrict__ Wk,
    const float* __restrict__ Wv, const float* __restrict__ Wo,
    float* __restrict__ M1, unsigned short* __restrict__ M2F) {
  __shared__ float rowbuf[128];
  int bid = blockIdx.x, tid = threadIdx.x;
  if (bid < 256) {
    if (tid < 128) rowbuf[tid] = Wq[bid * 128 + tid];
    __syncthreads();
    const float4* Wk4 = (const float4*)Wk;
    const float4* rb4 = (const float4*)rowbuf;
    float acc = 0.f;
#pragma unroll 8
    for (int k4 = 0; k4 < 32; ++k4) {
      float4 a = rb4[k4];
      float4 b = Wk4[tid * 32 + k4];
      acc = fmaf(a.x, b.x, acc); acc = fmaf(a.y, b.y, acc);
      acc = fmaf(a.z, b.z, acc); acc = fmaf(a.w, b.w, acc);
    }
    M1[bid * 256 + tid] = acc;
  } else {
    int k = bid - 256;  // M2 row index
    if (tid < 128) rowbuf[tid] = Wv[k * 128 + tid];
    __syncthreads();
    float acc = 0.f;
#pragma unroll 8
    for (int kk = 0; kk < 128; ++kk)
      acc = fmaf(rowbuf[kk], Wo[kk * 256 + tid], acc);
    // MFMA B-frag: frag(ct,kt): lane l holds B[kt*32+(l>>4)*8+i][ct*16+(l&15)]
    int c = tid;
    int ct = c >> 4, kt = k >> 5, lh = (k >> 3) & 3, i = k & 7, lm = c & 15;
    M2F[(size_t)(((ct * 8 + kt) * 64 + lh * 16 + lm) * 8 + i)] = f2bf(acc);
  }
}

// ---------------- Mega-kernel ---------------------------------------------
// 64 pixels/block, 4 waves, wave w owns rows r0=w*16..r0+15 (phases 0,1c,2).
__global__ __launch_bounds__(256, 2) void fused_all(
    const float* __restrict__ query, const float* __restrict__ hist,
    const float* __restrict__ M1, const unsigned short* __restrict__ M2F,
    float* __restrict__ OUT) {
  __shared__ float As[64][260];      // query -> qm -> hbar
  __shared__ float scoresS[64][17];  // [pixel][t] (pad 17)
  __shared__ float attnW[64][4];
  __shared__ int attnT[64][4];
  int tid = threadIdx.x;
  int l = tid & 63;
  int w = tid >> 6;
  int pix0 = blockIdx.x * 64;
  int r0 = w * 16;

  const float4* H4 = (const float4*)hist;
  int b = pix0 >> 12;
  int off0 = pix0 & 4095;
  int bT = b * 16;
  int t_mine = l & 15;
  int gbase = l & 48;

  // ---------- phase 0: own 16 rows of qm = query @ M1 (fp32) ----------
  {
    const float4* Qb4 = (const float4*)(query + (size_t)pix0 * 256);
#pragma unroll
    for (int k = 0; k < 16; ++k)
      *(float4*)&As[r0 + k][4 * l] = Qb4[(size_t)(r0 + k) * 64 + l];
    float4 acc[16];
#pragma unroll
    for (int j = 0; j < 16; ++j) acc[j] = make_float4(0.f, 0.f, 0.f, 0.f);
    const float4* B4 = (const float4*)M1;
#pragma unroll 4
    for (int d = 0; d < 256; ++d) {
      float4 bv = B4[d * 64 + l];
#pragma unroll
      for (int j = 0; j < 16; ++j) {
        float a = As[r0 + j][d];  // uniform -> LDS broadcast
        acc[j].x = fmaf(a, bv.x, acc[j].x);
        acc[j].y = fmaf(a, bv.y, acc[j].y);
        acc[j].z = fmaf(a, bv.z, acc[j].z);
        acc[j].w = fmaf(a, bv.w, acc[j].w);
      }
    }
#pragma unroll
    for (int j = 0; j < 16; ++j)
      *(float4*)&As[r0 + j][4 * l] = acc[j];
  }
  __syncthreads();

  // ---------- phase 1a: linear score pass (t-major, contiguous runs) ------
  // wave w: t in {w, w+4, w+8, w+12}; per t, 64 pixels = 64KB contiguous.
  for (int tt = 0; tt < 4; ++tt) {
    int t = w + 4 * tt;
    size_t base = ((size_t)(bT + t) * 4096 + off0) * 64 + l;
    float4 h[8], hn[8];
#pragma unroll
    for (int j = 0; j < 8; ++j) h[j] = H4[base + (size_t)j * 64];
    for (int p8 = 0; p8 < 8; ++p8) {
      if (p8 < 7) {
#pragma unroll
        for (int j = 0; j < 8; ++j)
          hn[j] = H4[base + (size_t)(p8 * 8 + 8 + j) * 64];
      }
#pragma unroll
      for (int j = 0; j < 8; ++j) {
        int p = p8 * 8 + j;
        float4 q = *(const float4*)&As[p][4 * l];
        float s = h[j].x * q.x;
        s = fmaf(h[j].y, q.y, s);
        s = fmaf(h[j].z, q.z, s);
        s = fmaf(h[j].w, q.w, s);
        s += __shfl_xor(s, 1);
        s += __shfl_xor(s, 2);
        s += __shfl_xor(s, 4);
        s += __shfl_xor(s, 8);
        s += __shfl_xor(s, 16);
        s += __shfl_xor(s, 32);
        if (l == 0) scoresS[p][t] = s * 0.08838834764831845f;
      }
#pragma unroll
      for (int j = 0; j < 8; ++j) h[j] = hn[j];
    }
  }
  __syncthreads();

  // ---------- phase 1b: top-4 + decay bias + softmax (own 16 pixels) ------
#pragma unroll
  for (int i = 0; i < 4; ++i) {
    int p = r0 + 4 * i + (l >> 4);  // 4 pixels x 16-lane groups
    float sc = scoresS[p][t_mine];
    int rank = 0;
#pragma unroll
    for (int k = 1; k < 16; ++k) {
      int ot = (t_mine + k) & 15;
      float o = __shfl(sc, gbase | ot);
      rank += (o > sc) || (o == sc && ot < t_mine);
    }
    bool chosen = rank < 4;
    float earg = sc + (float)(16 - t_mine) * -0.05129329438755058f;
    float ex = chosen ? expf(earg) : 0.0f;
    float Z = ex;
    Z += __shfl_xor(Z, 1);
    Z += __shfl_xor(Z, 2);
    Z += __shfl_xor(Z, 4);
    Z += __shfl_xor(Z, 8);
    unsigned long long bal = __ballot(chosen);
    int before =
        __popcll(bal & (((1ull << l) - 1)) & (0xFFFFull << gbase));
    if (chosen) {
      attnW[p][before] = ex / Z;
      attnT[p][before] = t_mine;
    }
  }
  // own pixels' attn written by this wave only -> no barrier needed

  // ---------- phase 1c: gather 4 winner rows per pixel -> hbar -> As ------
#pragma unroll 2
  for (int i = 0; i < 16; i += 2) {
    int p0 = r0 + i;
    float aW[2][4];
    int aT[2][4];
#pragma unroll
    for (int u = 0; u < 2; ++u)
#pragma unroll
      for (int j = 0; j < 4; ++j) {
        aW[u][j] = attnW[p0 + u][j];  // uniform -> broadcast
        aT[u][j] = attnT[p0 + u][j];
      }
    float4 hv[2][4];
#pragma unroll
    for (int u = 0; u < 2; ++u)
#pragma unroll
      for (int j = 0; j < 4; ++j)
        hv[u][j] =
            H4[((size_t)(bT + aT[u][j]) * 4096 + off0 + p0 + u) * 64 + l];
#pragma unroll
    for (int u = 0; u < 2; ++u) {
      float4 acc;
      acc.x = aW[u][0] * hv[u][0].x;
      acc.y = aW[u][0] * hv[u][0].y;
      acc.z = aW[u][0] * hv[u][0].z;
      acc.w = aW[u][0] * hv[u][0].w;
#pragma unroll
      for (int j = 1; j < 4; ++j) {
        acc.x = fmaf(aW[u][j], hv[u][j].x, acc.x);
        acc.y = fmaf(aW[u][j], hv[u][j].y, acc.y);
        acc.z = fmaf(aW[u][j], hv[u][j].z, acc.z);
        acc.w = fmaf(aW[u][j], hv[u][j].w, acc.w);
      }
      *(float4*)&As[p0 + u][4 * l] = acc;  // row wave-owned
    }
  }

  // ---------- phase 2: OUT rows r0..r0+15 = As(hbar) @ M2 via bf16 MFMA ---
  {
    int lm = l & 15, lh = l >> 4;
    const bf16x8* B8 = (const bf16x8*)M2F;
    f32x4 acc[16];
#pragma unroll
    for (int ct = 0; ct < 16; ++ct) acc[ct] = (f32x4){0.f, 0.f, 0.f, 0.f};
#pragma unroll
    for (int kt = 0; kt < 8; ++kt) {
      const float* ap = &As[r0 + lm][kt * 32 + lh * 8];
      float4 a0 = *(const float4*)ap;
      float4 a1 = *(const float4*)(ap + 4);
      bf16x8 afrag;
      afrag[0] = (short)f2bf(a0.x); afrag[1] = (short)f2bf(a0.y);
      afrag[2] = (short)f2bf(a0.z); afrag[3] = (short)f2bf(a0.w);
      afrag[4] = (short)f2bf(a1.x); afrag[5] = (short)f2bf(a1.y);
      afrag[6] = (short)f2bf(a1.z); afrag[7] = (short)f2bf(a1.w);
#pragma unroll
      for (int ct = 0; ct < 16; ++ct) {
        bf16x8 bfrag = B8[(ct * 8 + kt) * 64 + l];
        acc[ct] = __builtin_amdgcn_mfma_f32_16x16x32_bf16(afrag, bfrag,
                                                          acc[ct], 0, 0, 0);
      }
    }
    float* outp = OUT + (size_t)pix0 * 256;
#pragma unroll
    for (int ct = 0; ct < 16; ++ct) {
#pragma unroll
      for (int j = 0; j < 4; ++j)
        outp[(size_t)(r0 + lh * 4 + j) * 256 + ct * 16 + lm] = acc[ct][j];
    }
  }
}

// --------------------------------------------------------------------------
extern "C" void kernel_launch(void* const* d_in, const int* in_sizes, int n_in,
                              void* d_out, int out_size, void* d_ws,
                              size_t ws_size, hipStream_t stream) {
  const float* query = (const float*)d_in[0];  // [8,64,64,256]
  const float* hist = (const float*)d_in[1];   // [8,16,64,64,256]
  const float* Wq = (const float*)d_in[2];     // [256,128]
  const float* Wk = (const float*)d_in[3];     // [256,128]
  const float* Wv = (const float*)d_in[4];     // [256,128]
  const float* Wo = (const float*)d_in[5];     // [128,256]
  float* out = (float*)d_out;                  // [32768,256]

  float* ws = (float*)d_ws;
  float* M1 = ws;  // 65536 floats
  unsigned short* M2F = (unsigned short*)(ws + 65536);  // bf16 frag order

  precompute_weights<<<512, 256, 0, stream>>>(Wq, Wk, Wv, Wo, M1, M2F);
  fused_all<<<512, 256, 0, stream>>>(query, hist, M1, M2F, out);
}

// Round 17
// 158.463 us; speedup vs baseline: 1.2483x; 1.2483x over previous
//
#include <hip/hip_runtime.h>
#include <math.h>

// Shapes: B=8, T=16, H=64, W=64, D=256, DK=128, TOP_K=4
// pixels N = B*H*W = 32768 (4096 per batch)
//
// Factorization: out = (sum_t attn_t * hist_t) @ (Wv@Wo)
//                score_t = (q @ (Wq@Wk^T)) . hist_t / sqrt(128)
//
// R17 = R13 champion (64px/block, stream rows {w+4i}, reg dbuf, bf16-MFMA
// out-projection) + phase 0 on MFMA with a 3-LEVEL bf16 split (24 mantissa
// bits, 8 products >= 2^-24; residual == fp32-reorder noise, R13 class --
// R16's 2-level/3-product split at ~1e-5 flipped one top-4 and failed) and
// COLUMN-SPLIT work assignment (wave w -> qm cols [64w,64w+64) of all 64
// rows) cutting M1 L2 traffic 4x vs R16. 3 barriers in phase 0 only.

typedef __attribute__((ext_vector_type(8))) short bf16x8;
typedef __attribute__((ext_vector_type(4))) float f32x4;

__device__ inline unsigned short f2bf(float f) {
  union { float f; unsigned u; } v; v.f = f;
  unsigned r = (v.u + 0x7FFF + ((v.u >> 16) & 1)) >> 16;  // RNE
  return (unsigned short)r;
}
__device__ inline float bf2f(unsigned short h) {
  union { unsigned u; float f; } v; v.u = ((unsigned)h) << 16;
  return v.f;
}

// --- Kernel P: M1A/B/C = 3-level bf16 split-frag(Wq@Wk^T), M2F bf16-frag --
__global__ __launch_bounds__(256) void precompute_weights(
    const float* __restrict__ Wq, const float* __restrict__ Wk,
    const float* __restrict__ Wv, const float* __restrict__ Wo,
    unsigned short* __restrict__ M1A, unsigned short* __restrict__ M1B,
    unsigned short* __restrict__ M1C, unsigned short* __restrict__ M2F) {
  __shared__ float rowbuf[128];
  int bid = blockIdx.x, tid = threadIdx.x;
  if (bid < 256) {
    int d = bid;  // contraction index of qm GEMM
    if (tid < 128) rowbuf[tid] = Wq[d * 128 + tid];
    __syncthreads();
    const float4* Wk4 = (const float4*)Wk;
    const float4* rb4 = (const float4*)rowbuf;
    float acc = 0.f;
#pragma unroll 8
    for (int k4 = 0; k4 < 32; ++k4) {
      float4 a = rb4[k4];
      float4 b = Wk4[tid * 32 + k4];
      acc = fmaf(a.x, b.x, acc); acc = fmaf(a.y, b.y, acc);
      acc = fmaf(a.z, b.z, acc); acc = fmaf(a.w, b.w, acc);
    }
    // B-frag: frag(ct,kt): lane l holds B[kt*32+(l>>4)*8+i][ct*16+(l&15)]
    int c = tid;
    int ct = c >> 4, kt = d >> 5, lh = (d >> 3) & 3, i = d & 7, lm = c & 15;
    size_t idx = (size_t)(((ct * 8 + kt) * 64 + lh * 16 + lm) * 8 + i);
    unsigned short h0 = f2bf(acc);
    float r1 = acc - bf2f(h0);
    unsigned short h1 = f2bf(r1);
    float r2 = r1 - bf2f(h1);
    M1A[idx] = h0;
    M1B[idx] = h1;
    M1C[idx] = f2bf(r2);
  } else {
    int k = bid - 256;  // M2 row index
    if (tid < 128) rowbuf[tid] = Wv[k * 128 + tid];
    __syncthreads();
    float acc = 0.f;
#pragma unroll 8
    for (int kk = 0; kk < 128; ++kk)
      acc = fmaf(rowbuf[kk], Wo[kk * 256 + tid], acc);
    int c = tid;
    int ct = c >> 4, kt = k >> 5, lh = (k >> 3) & 3, i = k & 7, lm = c & 15;
    M2F[(size_t)(((ct * 8 + kt) * 64 + lh * 16 + lm) * 8 + i)] = f2bf(acc);
  }
}

// ---------------- Mega-kernel: MFMA qm -> attention -> MFMA out -----------
__global__ __launch_bounds__(256, 2) void fused_all(
    const float* __restrict__ query, const float* __restrict__ hist,
    const unsigned short* __restrict__ M1A,
    const unsigned short* __restrict__ M1B,
    const unsigned short* __restrict__ M1C,
    const unsigned short* __restrict__ M2F, float* __restrict__ OUT) {
  __shared__ float As[64][260];  // query -> qm -> hbar
  int tid = threadIdx.x;
  int l = tid & 63;
  int w = tid >> 6;
  int pix0 = blockIdx.x * 64;
  int lm = l & 15, lh = l >> 4;

  const float4* H4 = (const float4*)hist;
  int b = pix0 >> 12;
  int off0 = pix0 & 4095;
  size_t hblk = ((size_t)b * 16 * 4096 + off0) * 64 + l;
  int t_mine = l & 15;
  int gbase = l & 48;

  // ---- prefetch pixel 0 (row w): lands under the whole of phase 0 ----
  float4 hA[16], hB[16];
#pragma unroll
  for (int t = 0; t < 16; ++t)
    hA[t] = H4[hblk + (size_t)w * 64 + (size_t)t * 262144];

  // ---------- phase 0: qm = query @ M1, 3-level-split bf16 MFMA -----------
  {
    const float* Qb = query + (size_t)pix0 * 256;
    for (int i = tid; i < 64 * 256; i += 256)
      As[i >> 8][i & 255] = Qb[i];
    __syncthreads();

    const bf16x8* BA = (const bf16x8*)M1A;
    const bf16x8* BB = (const bf16x8*)M1B;
    const bf16x8* BC = (const bf16x8*)M1C;
    f32x4 qacc[16];  // tile (rt, cc) -> qacc[rt*4+cc]
#pragma unroll
    for (int i = 0; i < 16; ++i) qacc[i] = (f32x4){0.f, 0.f, 0.f, 0.f};
#pragma unroll
    for (int kt = 0; kt < 8; ++kt) {
      bf16x8 qa[4], qb[4], qc[4];  // A-splits for 4 row-tiles
#pragma unroll
      for (int rt = 0; rt < 4; ++rt) {
        const float* ap = &As[rt * 16 + lm][kt * 32 + lh * 8];
        float4 a0 = *(const float4*)ap;
        float4 a1 = *(const float4*)(ap + 4);
        float av[8] = {a0.x, a0.y, a0.z, a0.w, a1.x, a1.y, a1.z, a1.w};
#pragma unroll
        for (int e = 0; e < 8; ++e) {
          unsigned short h0 = f2bf(av[e]);
          float r1 = av[e] - bf2f(h0);
          unsigned short h1 = f2bf(r1);
          float r2 = r1 - bf2f(h1);
          qa[rt][e] = (short)h0;
          qb[rt][e] = (short)h1;
          qc[rt][e] = (short)f2bf(r2);
        }
      }
#pragma unroll
      for (int cc = 0; cc < 4; ++cc) {
        int ct = w * 4 + cc;
        bf16x8 ba = BA[(ct * 8 + kt) * 64 + l];
        bf16x8 bb = BB[(ct * 8 + kt) * 64 + l];
        bf16x8 bc = BC[(ct * 8 + kt) * 64 + l];
#pragma unroll
        for (int rt = 0; rt < 4; ++rt) {
          f32x4 a = qacc[rt * 4 + cc];
          a = __builtin_amdgcn_mfma_f32_16x16x32_bf16(qa[rt], ba, a, 0, 0, 0);
          a = __builtin_amdgcn_mfma_f32_16x16x32_bf16(qa[rt], bb, a, 0, 0, 0);
          a = __builtin_amdgcn_mfma_f32_16x16x32_bf16(qb[rt], ba, a, 0, 0, 0);
          a = __builtin_amdgcn_mfma_f32_16x16x32_bf16(qa[rt], bc, a, 0, 0, 0);
          a = __builtin_amdgcn_mfma_f32_16x16x32_bf16(qb[rt], bb, a, 0, 0, 0);
          a = __builtin_amdgcn_mfma_f32_16x16x32_bf16(qc[rt], ba, a, 0, 0, 0);
          a = __builtin_amdgcn_mfma_f32_16x16x32_bf16(qb[rt], bc, a, 0, 0, 0);
          a = __builtin_amdgcn_mfma_f32_16x16x32_bf16(qc[rt], bb, a, 0, 0, 0);
          qacc[rt * 4 + cc] = a;
        }
      }
    }
    __syncthreads();  // all query reads done before overwrite
    // C/D: tile (rt,cc): row = rt*16 + lh*4 + j, col = w*64 + cc*16 + lm
#pragma unroll
    for (int rt = 0; rt < 4; ++rt)
#pragma unroll
      for (int cc = 0; cc < 4; ++cc)
#pragma unroll
        for (int j = 0; j < 4; ++j)
          As[rt * 16 + lh * 4 + j][w * 64 + cc * 16 + lm] =
              qacc[rt * 4 + cc][j];
    __syncthreads();  // qm complete (cols written by all waves)
  }

  // ---------- phase 1: stream hist, score, top-4, softmax, hbar -----------
#define ATTN_STEP(HC, HN, IT, DOPRE)                                        \
  {                                                                         \
    int row = w + 4 * (IT);                                                 \
    if (DOPRE) { /* prefetch next pixel (row+4) into HN */                  \
      size_t nb = hblk + (size_t)(row + 4) * 64;                            \
      _Pragma("unroll") for (int t = 0; t < 16; ++t)                        \
          HN[t] = H4[nb + (size_t)t * 262144];                              \
    }                                                                       \
    float4 q = *(const float4*)&As[row][4 * l];                             \
    float part[16];                                                         \
    _Pragma("unroll") for (int t = 0; t < 16; ++t) {                        \
      float s = HC[t].x * q.x;                                              \
      s = fmaf(HC[t].y, q.y, s);                                            \
      s = fmaf(HC[t].z, q.z, s);                                            \
      s = fmaf(HC[t].w, q.w, s);                                            \
      part[t] = s;                                                          \
    }                                                                       \
    _Pragma("unroll") for (int st = 0; st < 4; ++st) {                      \
      bool hi = (l >> st) & 1;                                              \
      int nt = 8 >> st;                                                     \
      _Pragma("unroll") for (int i = 0; i < nt; ++i) {                      \
        float mine = hi ? part[2 * i + 1] : part[2 * i];                    \
        float oth = hi ? part[2 * i] : part[2 * i + 1];                     \
        part[i] = mine + __shfl_xor(oth, 1 << st);                          \
      }                                                                     \
    }                                                                       \
    float v = part[0];                                                      \
    v += __shfl_xor(v, 16);                                                 \
    v += __shfl_xor(v, 32);                                                 \
    float sc = v * 0.08838834764831845f; /* 1/sqrt(128); t = l&15 */        \
    int rank = 0; /* exact lax.top_k: lowest-index tie-break */             \
    _Pragma("unroll") for (int k = 1; k < 16; ++k) {                        \
      int ot = (t_mine + k) & 15;                                           \
      float o = __shfl(sc, gbase | ot);                                     \
      rank += (o > sc) || (o == sc && ot < t_mine);                         \
    }                                                                       \
    bool chosen = rank < 4;                                                 \
    float earg = sc + (float)(16 - t_mine) * -0.05129329438755058f;         \
    float ex = chosen ? expf(earg) : 0.0f;                                  \
    float Z = ex;                                                           \
    Z += __shfl_xor(Z, 1);                                                  \
    Z += __shfl_xor(Z, 2);                                                  \
    Z += __shfl_xor(Z, 4);                                                  \
    Z += __shfl_xor(Z, 8);                                                  \
    float attn = ex / Z;                                                    \
    float4 hb = make_float4(0.f, 0.f, 0.f, 0.f);                            \
    _Pragma("unroll") for (int t = 0; t < 16; ++t) {                        \
      float a = __shfl(attn, gbase | t); /* uniform in value across wave */ \
      if (a != 0.0f) {                                                      \
        hb.x = fmaf(a, HC[t].x, hb.x);                                      \
        hb.y = fmaf(a, HC[t].y, hb.y);                                      \
        hb.z = fmaf(a, HC[t].z, hb.z);                                      \
        hb.w = fmaf(a, HC[t].w, hb.w);                                      \
      }                                                                     \
    }                                                                       \
    *(float4*)&As[row][4 * l] = hb; /* q already in reg; row wave-owned */  \
  }

  for (int it2 = 0; it2 < 8; ++it2) {
    ATTN_STEP(hA, hB, 2 * it2, true);
    ATTN_STEP(hB, hA, 2 * it2 + 1, it2 < 7);
  }
#undef ATTN_STEP

  // ---------- phase 2: OUT rows {w+4i} = As(hbar) @ M2 via bf16 MFMA ------
  {
    const bf16x8* B8 = (const bf16x8*)M2F;
    f32x4 acc[16];
#pragma unroll
    for (int ct = 0; ct < 16; ++ct) acc[ct] = (f32x4){0.f, 0.f, 0.f, 0.f};
#pragma unroll
    for (int kt = 0; kt < 8; ++kt) {
      const float* ap = &As[w + 4 * lm][kt * 32 + lh * 8];
      float4 a0 = *(const float4*)ap;
      float4 a1 = *(const float4*)(ap + 4);
      bf16x8 afrag;
      afrag[0] = (short)f2bf(a0.x); afrag[1] = (short)f2bf(a0.y);
      afrag[2] = (short)f2bf(a0.z); afrag[3] = (short)f2bf(a0.w);
      afrag[4] = (short)f2bf(a1.x); afrag[5] = (short)f2bf(a1.y);
      afrag[6] = (short)f2bf(a1.z); afrag[7] = (short)f2bf(a1.w);
#pragma unroll
      for (int ct = 0; ct < 16; ++ct) {
        bf16x8 bfrag = B8[(ct * 8 + kt) * 64 + l];
        acc[ct] = __builtin_amdgcn_mfma_f32_16x16x32_bf16(afrag, bfrag,
                                                          acc[ct], 0, 0, 0);
      }
    }
    float* outp = OUT + (size_t)pix0 * 256;
#pragma unroll
    for (int ct = 0; ct < 16; ++ct) {
#pragma unroll
      for (int j = 0; j < 4; ++j)
        outp[(size_t)(w + 4 * (lh * 4 + j)) * 256 + ct * 16 + lm] =
            acc[ct][j];
    }
  }
}

// --------------------------------------------------------------------------
extern "C" void kernel_launch(void* const* d_in, const int* in_sizes, int n_in,
                              void* d_out, int out_size, void* d_ws,
                              size_t ws_size, hipStream_t stream) {
  const float* query = (const float*)d_in[0];  // [8,64,64,256]
  const float* hist = (const float*)d_in[1];   // [8,16,64,64,256]
  const float* Wq = (const float*)d_in[2];     // [256,128]
  const float* Wk = (const float*)d_in[3];     // [256,128]
  const float* Wv = (const float*)d_in[4];     // [256,128]
  const float* Wo = (const float*)d_in[5];     // [128,256]
  float* out = (float*)d_out;                  // [32768,256]

  unsigned short* wsu = (unsigned short*)d_ws;
  unsigned short* M1A = wsu;           // 65536 bf16 (frag order)
  unsigned short* M1B = wsu + 65536;   // 65536 bf16
  unsigned short* M1C = wsu + 131072;  // 65536 bf16
  unsigned short* M2F = wsu + 196608;  // 65536 bf16

  precompute_weights<<<512, 256, 0, stream>>>(Wq, Wk, Wv, Wo, M1A, M1B, M1C,
                                              M2F);
  fused_all<<<512, 256, 0, stream>>>(query, hist, M1A, M1B, M1C, M2F, out);
}

// Round 18
// 140.052 us; speedup vs baseline: 1.4124x; 1.1315x over previous
//
#include <hip/hip_runtime.h>
#include <math.h>

// Shapes: B=8, T=16, H=64, W=64, D=256, DK=128, TOP_K=4
// pixels N = B*H*W = 32768 (4096 per batch)
//
// Factorization: out = (sum_t attn_t * hist_t) @ (Wv@Wo)
//                score_t = (q @ (Wq@Wk^T)) . hist_t / sqrt(128)
//
// R18 = R17 champion (MFMA 3-level-split qm, reg-dbuf strided stream,
// bf16-MFMA out-projection) + NON-TEMPORAL loads on the hist stream
// (512 MB single-use data; nt bypasses L1/L2/L3 allocation). All
// arithmetic bit-identical to R17.

typedef __attribute__((ext_vector_type(8))) short bf16x8;
typedef __attribute__((ext_vector_type(4))) float f32x4;

__device__ inline unsigned short f2bf(float f) {
  union { float f; unsigned u; } v; v.f = f;
  unsigned r = (v.u + 0x7FFF + ((v.u >> 16) & 1)) >> 16;  // RNE
  return (unsigned short)r;
}
__device__ inline float bf2f(unsigned short h) {
  union { unsigned u; float f; } v; v.u = ((unsigned)h) << 16;
  return v.f;
}
__device__ inline float4 ldnt(const float4* p) {
  f32x4 t = __builtin_nontemporal_load((const f32x4*)p);
  return make_float4(t[0], t[1], t[2], t[3]);
}

// --- Kernel P: M1A/B/C = 3-level bf16 split-frag(Wq@Wk^T), M2F bf16-frag --
__global__ __launch_bounds__(256) void precompute_weights(
    const float* __restrict__ Wq, const float* __restrict__ Wk,
    const float* __restrict__ Wv, const float* __restrict__ Wo,
    unsigned short* __restrict__ M1A, unsigned short* __restrict__ M1B,
    unsigned short* __restrict__ M1C, unsigned short* __restrict__ M2F) {
  __shared__ float rowbuf[128];
  int bid = blockIdx.x, tid = threadIdx.x;
  if (bid < 256) {
    int d = bid;  // contraction index of qm GEMM
    if (tid < 128) rowbuf[tid] = Wq[d * 128 + tid];
    __syncthreads();
    const float4* Wk4 = (const float4*)Wk;
    const float4* rb4 = (const float4*)rowbuf;
    float acc = 0.f;
#pragma unroll 8
    for (int k4 = 0; k4 < 32; ++k4) {
      float4 a = rb4[k4];
      float4 b = Wk4[tid * 32 + k4];
      acc = fmaf(a.x, b.x, acc); acc = fmaf(a.y, b.y, acc);
      acc = fmaf(a.z, b.z, acc); acc = fmaf(a.w, b.w, acc);
    }
    // B-frag: frag(ct,kt): lane l holds B[kt*32+(l>>4)*8+i][ct*16+(l&15)]
    int c = tid;
    int ct = c >> 4, kt = d >> 5, lh = (d >> 3) & 3, i = d & 7, lm = c & 15;
    size_t idx = (size_t)(((ct * 8 + kt) * 64 + lh * 16 + lm) * 8 + i);
    unsigned short h0 = f2bf(acc);
    float r1 = acc - bf2f(h0);
    unsigned short h1 = f2bf(r1);
    float r2 = r1 - bf2f(h1);
    M1A[idx] = h0;
    M1B[idx] = h1;
    M1C[idx] = f2bf(r2);
  } else {
    int k = bid - 256;  // M2 row index
    if (tid < 128) rowbuf[tid] = Wv[k * 128 + tid];
    __syncthreads();
    float acc = 0.f;
#pragma unroll 8
    for (int kk = 0; kk < 128; ++kk)
      acc = fmaf(rowbuf[kk], Wo[kk * 256 + tid], acc);
    int c = tid;
    int ct = c >> 4, kt = k >> 5, lh = (k >> 3) & 3, i = k & 7, lm = c & 15;
    M2F[(size_t)(((ct * 8 + kt) * 64 + lh * 16 + lm) * 8 + i)] = f2bf(acc);
  }
}

// ---------------- Mega-kernel: MFMA qm -> attention -> MFMA out -----------
__global__ __launch_bounds__(256, 2) void fused_all(
    const float* __restrict__ query, const float* __restrict__ hist,
    const unsigned short* __restrict__ M1A,
    const unsigned short* __restrict__ M1B,
    const unsigned short* __restrict__ M1C,
    const unsigned short* __restrict__ M2F, float* __restrict__ OUT) {
  __shared__ float As[64][260];  // query -> qm -> hbar
  int tid = threadIdx.x;
  int l = tid & 63;
  int w = tid >> 6;
  int pix0 = blockIdx.x * 64;
  int lm = l & 15, lh = l >> 4;

  const float4* H4 = (const float4*)hist;
  int b = pix0 >> 12;
  int off0 = pix0 & 4095;
  size_t hblk = ((size_t)b * 16 * 4096 + off0) * 64 + l;
  int t_mine = l & 15;
  int gbase = l & 48;

  // ---- prefetch pixel 0 (row w): lands under the whole of phase 0 ----
  float4 hA[16], hB[16];
#pragma unroll
  for (int t = 0; t < 16; ++t)
    hA[t] = ldnt(&H4[hblk + (size_t)w * 64 + (size_t)t * 262144]);

  // ---------- phase 0: qm = query @ M1, 3-level-split bf16 MFMA -----------
  {
    const float* Qb = query + (size_t)pix0 * 256;
    for (int i = tid; i < 64 * 256; i += 256)
      As[i >> 8][i & 255] = Qb[i];
    __syncthreads();

    const bf16x8* BA = (const bf16x8*)M1A;
    const bf16x8* BB = (const bf16x8*)M1B;
    const bf16x8* BC = (const bf16x8*)M1C;
    f32x4 qacc[16];  // tile (rt, cc) -> qacc[rt*4+cc]
#pragma unroll
    for (int i = 0; i < 16; ++i) qacc[i] = (f32x4){0.f, 0.f, 0.f, 0.f};
#pragma unroll
    for (int kt = 0; kt < 8; ++kt) {
      bf16x8 qa[4], qb[4], qc[4];  // A-splits for 4 row-tiles
#pragma unroll
      for (int rt = 0; rt < 4; ++rt) {
        const float* ap = &As[rt * 16 + lm][kt * 32 + lh * 8];
        float4 a0 = *(const float4*)ap;
        float4 a1 = *(const float4*)(ap + 4);
        float av[8] = {a0.x, a0.y, a0.z, a0.w, a1.x, a1.y, a1.z, a1.w};
#pragma unroll
        for (int e = 0; e < 8; ++e) {
          unsigned short h0 = f2bf(av[e]);
          float r1 = av[e] - bf2f(h0);
          unsigned short h1 = f2bf(r1);
          float r2 = r1 - bf2f(h1);
          qa[rt][e] = (short)h0;
          qb[rt][e] = (short)h1;
          qc[rt][e] = (short)f2bf(r2);
        }
      }
#pragma unroll
      for (int cc = 0; cc < 4; ++cc) {
        int ct = w * 4 + cc;
        bf16x8 ba = BA[(ct * 8 + kt) * 64 + l];
        bf16x8 bb = BB[(ct * 8 + kt) * 64 + l];
        bf16x8 bc = BC[(ct * 8 + kt) * 64 + l];
#pragma unroll
        for (int rt = 0; rt < 4; ++rt) {
          f32x4 a = qacc[rt * 4 + cc];
          a = __builtin_amdgcn_mfma_f32_16x16x32_bf16(qa[rt], ba, a, 0, 0, 0);
          a = __builtin_amdgcn_mfma_f32_16x16x32_bf16(qa[rt], bb, a, 0, 0, 0);
          a = __builtin_amdgcn_mfma_f32_16x16x32_bf16(qb[rt], ba, a, 0, 0, 0);
          a = __builtin_amdgcn_mfma_f32_16x16x32_bf16(qa[rt], bc, a, 0, 0, 0);
          a = __builtin_amdgcn_mfma_f32_16x16x32_bf16(qb[rt], bb, a, 0, 0, 0);
          a = __builtin_amdgcn_mfma_f32_16x16x32_bf16(qc[rt], ba, a, 0, 0, 0);
          a = __builtin_amdgcn_mfma_f32_16x16x32_bf16(qb[rt], bc, a, 0, 0, 0);
          a = __builtin_amdgcn_mfma_f32_16x16x32_bf16(qc[rt], bb, a, 0, 0, 0);
          qacc[rt * 4 + cc] = a;
        }
      }
    }
    __syncthreads();  // all query reads done before overwrite
    // C/D: tile (rt,cc): row = rt*16 + lh*4 + j, col = w*64 + cc*16 + lm
#pragma unroll
    for (int rt = 0; rt < 4; ++rt)
#pragma unroll
      for (int cc = 0; cc < 4; ++cc)
#pragma unroll
        for (int j = 0; j < 4; ++j)
          As[rt * 16 + lh * 4 + j][w * 64 + cc * 16 + lm] =
              qacc[rt * 4 + cc][j];
    __syncthreads();  // qm complete (cols written by all waves)
  }

  // ---------- phase 1: stream hist (nt loads), score, top-4, hbar ---------
#define ATTN_STEP(HC, HN, IT, DOPRE)                                        \
  {                                                                         \
    int row = w + 4 * (IT);                                                 \
    if (DOPRE) { /* prefetch next pixel (row+4) into HN */                  \
      size_t nb = hblk + (size_t)(row + 4) * 64;                            \
      _Pragma("unroll") for (int t = 0; t < 16; ++t)                        \
          HN[t] = ldnt(&H4[nb + (size_t)t * 262144]);                       \
    }                                                                       \
    float4 q = *(const float4*)&As[row][4 * l];                             \
    float part[16];                                                         \
    _Pragma("unroll") for (int t = 0; t < 16; ++t) {                        \
      float s = HC[t].x * q.x;                                              \
      s = fmaf(HC[t].y, q.y, s);                                            \
      s = fmaf(HC[t].z, q.z, s);                                            \
      s = fmaf(HC[t].w, q.w, s);                                            \
      part[t] = s;                                                          \
    }                                                                       \
    _Pragma("unroll") for (int st = 0; st < 4; ++st) {                      \
      bool hi = (l >> st) & 1;                                              \
      int nt = 8 >> st;                                                     \
      _Pragma("unroll") for (int i = 0; i < nt; ++i) {                      \
        float mine = hi ? part[2 * i + 1] : part[2 * i];                    \
        float oth = hi ? part[2 * i] : part[2 * i + 1];                     \
        part[i] = mine + __shfl_xor(oth, 1 << st);                          \
      }                                                                     \
    }                                                                       \
    float v = part[0];                                                      \
    v += __shfl_xor(v, 16);                                                 \
    v += __shfl_xor(v, 32);                                                 \
    float sc = v * 0.08838834764831845f; /* 1/sqrt(128); t = l&15 */        \
    int rank = 0; /* exact lax.top_k: lowest-index tie-break */             \
    _Pragma("unroll") for (int k = 1; k < 16; ++k) {                        \
      int ot = (t_mine + k) & 15;                                           \
      float o = __shfl(sc, gbase | ot);                                     \
      rank += (o > sc) || (o == sc && ot < t_mine);                         \
    }                                                                       \
    bool chosen = rank < 4;                                                 \
    float earg = sc + (float)(16 - t_mine) * -0.05129329438755058f;         \
    float ex = chosen ? expf(earg) : 0.0f;                                  \
    float Z = ex;                                                           \
    Z += __shfl_xor(Z, 1);                                                  \
    Z += __shfl_xor(Z, 2);                                                  \
    Z += __shfl_xor(Z, 4);                                                  \
    Z += __shfl_xor(Z, 8);                                                  \
    float attn = ex / Z;                                                    \
    float4 hb = make_float4(0.f, 0.f, 0.f, 0.f);                            \
    _Pragma("unroll") for (int t = 0; t < 16; ++t) {                        \
      float a = __shfl(attn, gbase | t); /* uniform in value across wave */ \
      if (a != 0.0f) {                                                      \
        hb.x = fmaf(a, HC[t].x, hb.x);                                      \
        hb.y = fmaf(a, HC[t].y, hb.y);                                      \
        hb.z = fmaf(a, HC[t].z, hb.z);                                      \
        hb.w = fmaf(a, HC[t].w, hb.w);                                      \
      }                                                                     \
    }                                                                       \
    *(float4*)&As[row][4 * l] = hb; /* q already in reg; row wave-owned */  \
  }

  for (int it2 = 0; it2 < 8; ++it2) {
    ATTN_STEP(hA, hB, 2 * it2, true);
    ATTN_STEP(hB, hA, 2 * it2 + 1, it2 < 7);
  }
#undef ATTN_STEP

  // ---------- phase 2: OUT rows {w+4i} = As(hbar) @ M2 via bf16 MFMA ------
  {
    const bf16x8* B8 = (const bf16x8*)M2F;
    f32x4 acc[16];
#pragma unroll
    for (int ct = 0; ct < 16; ++ct) acc[ct] = (f32x4){0.f, 0.f, 0.f, 0.f};
#pragma unroll
    for (int kt = 0; kt < 8; ++kt) {
      const float* ap = &As[w + 4 * lm][kt * 32 + lh * 8];
      float4 a0 = *(const float4*)ap;
      float4 a1 = *(const float4*)(ap + 4);
      bf16x8 afrag;
      afrag[0] = (short)f2bf(a0.x); afrag[1] = (short)f2bf(a0.y);
      afrag[2] = (short)f2bf(a0.z); afrag[3] = (short)f2bf(a0.w);
      afrag[4] = (short)f2bf(a1.x); afrag[5] = (short)f2bf(a1.y);
      afrag[6] = (short)f2bf(a1.z); afrag[7] = (short)f2bf(a1.w);
#pragma unroll
      for (int ct = 0; ct < 16; ++ct) {
        bf16x8 bfrag = B8[(ct * 8 + kt) * 64 + l];
        acc[ct] = __builtin_amdgcn_mfma_f32_16x16x32_bf16(afrag, bfrag,
                                                          acc[ct], 0, 0, 0);
      }
    }
    float* outp = OUT + (size_t)pix0 * 256;
#pragma unroll
    for (int ct = 0; ct < 16; ++ct) {
#pragma unroll
      for (int j = 0; j < 4; ++j)
        outp[(size_t)(w + 4 * (lh * 4 + j)) * 256 + ct * 16 + lm] =
            acc[ct][j];
    }
  }
}

// --------------------------------------------------------------------------
extern "C" void kernel_launch(void* const* d_in, const int* in_sizes, int n_in,
                              void* d_out, int out_size, void* d_ws,
                              size_t ws_size, hipStream_t stream) {
  const float* query = (const float*)d_in[0];  // [8,64,64,256]
  const float* hist = (const float*)d_in[1];   // [8,16,64,64,256]
  const float* Wq = (const float*)d_in[2];     // [256,128]
  const float* Wk = (const float*)d_in[3];     // [256,128]
  const float* Wv = (const float*)d_in[4];     // [256,128]
  const float* Wo = (const float*)d_in[5];     // [128,256]
  float* out = (float*)d_out;                  // [32768,256]

  unsigned short* wsu = (unsigned short*)d_ws;
  unsigned short* M1A = wsu;           // 65536 bf16 (frag order)
  unsigned short* M1B = wsu + 65536;   // 65536 bf16
  unsigned short* M1C = wsu + 131072;  // 65536 bf16
  unsigned short* M2F = wsu + 196608;  // 65536 bf16

  precompute_weights<<<512, 256, 0, stream>>>(Wq, Wk, Wv, Wo, M1A, M1B, M1C,
                                              M2F);
  fused_all<<<512, 256, 0, stream>>>(query, hist, M1A, M1B, M1C, M2F, out);
}